// Round 6
// baseline (122.607 us; speedup 1.0000x reference)
//
#include <hip/hip_runtime.h>
#include <hip/hip_bf16.h>

// SubbandCompose R6: DMA staging + p-split DFT + LDS overlay.
//
// y[t] = X[0] + (-1)^t X[64] + 2*sum_{m=1..63} X[m] cos(pi*m*t/64), t=0..64.
// p = min(t,64-t): E_p = sum_{even m} w_m X[m] c(m,p), O_p = odd-m sum.
//   y[p] = E_p + O_p,  y[64-p] = E_p - O_p.   (O_32=0 -> p=32 write-twice ok.)
// out[s,i,j] = (1/512)*sum_{k=0..5} filt[k*64+j]*y[i+5-k][t(k,j)],
//   t(k,j)=j (k even); (j==0?64:64-j) (k odd).
//
// Block = 128 thr = 2 waves = one 64-row chunk (59 frames), 2224 blocks.
// Stage X via global_load_lds width-16 (9 instr/wave, no VGPR roundtrip),
// stride-65 fp32 layout (odd stride -> 2-way banks, free). Lane=row reads its
// 65 X into VGPRs; wave w computes p-range [17w, 17w+17) with separate E/O
// accumulators (coefs via scalar pipe), writes y[p],y[64-p] bf16 into the
// SAME LDS (X region dead after reg read). Stage 2 = R5's rolling window.

#define NF 65
#define NT 8192
#define TRUE_LEN 8187
#define FPW 59
#define CPB 139            // chunks per batch element: ceil(8187/59)
#define TSTR 68            // coef table row stride (floats, 16B aligned)
#define YSTR 66            // Ys row stride (bf16)

typedef const __attribute__((address_space(4))) float cfloat;
typedef __attribute__((address_space(1))) const void gv_t;
typedef __attribute__((address_space(3))) void lv_t;

__device__ float d_tab[33 * TSTR];   // [p][m], m=0..64 (65..67 zero pad)

__global__ void build_tab_kernel() {
    int idx = blockIdx.x * 256 + threadIdx.x;
    if (idx >= 33 * TSTR) return;
    int p = idx / TSTR, m = idx - p * TSTR;
    float v = 0.0f;
    if (m < NF) {
        float w = (m == 0 || m == 64) ? 1.0f : 2.0f;
        int a = (m * p) & 127;                   // cos period 128
        v = w * cospif((float)a * (1.0f / 64.0f));
    }
    d_tab[idx] = v;
}

__device__ __forceinline__ void gl_lds16(const float* g, float* l) {
    __builtin_amdgcn_global_load_lds((gv_t*)g, (lv_t*)l, 16, 0, 0);
}
__device__ __forceinline__ void gl_lds4(const float* g, float* l) {
    __builtin_amdgcn_global_load_lds((gv_t*)g, (lv_t*)l, 4, 0, 0);
}

__global__ __launch_bounds__(128, 4)
void subband_main_kernel(const float* __restrict__ g_in,
                         const float* __restrict__ g_filt,
                         float* __restrict__ g_out)
{
    __shared__ float smem[64 * NF];                 // 16640 B; Ys overlays
    __hip_bfloat16* Yb = (__hip_bfloat16*)smem;     // 64 x YSTR bf16 (8448 B)

    const int tid  = threadIdx.x;       // 0..127
    const int lane = tid & 63;
    const int wv   = tid >> 6;
    const int cg   = blockIdx.x;
    const int s     = cg / CPB;
    const int fbase = (cg - s * CPB) * FPW;

    // ---- stage X rows fbase..fbase+63 (4160 dwords contiguous)
    if (fbase + 64 <= NT) {
        const float* src = g_in + ((size_t)s * NT + fbase) * NF;
        for (int c = wv; c < 16; c += 2)            // 8 x 1KB chunks per wave
            gl_lds16(src + c * 256 + lane * 4, smem + c * 256);
        if (wv == 0)                                // 256B tail (dwords 4096..4159)
            gl_lds4(src + 4096 + lane, smem + 4096);
    } else {
        // last chunk per batch: clamped scalar path (16 blocks total)
        const float* src = g_in + (size_t)s * NT * NF;
        for (int i = tid; i < 64 * NF; i += 128) {
            int r = i / NF, c = i - r * NF;
            int h = fbase + r; if (h > NT - 1) h = NT - 1;
            smem[i] = src[(size_t)h * NF + c];      // smem[r*65+c] == smem[i]
        }
    }
    __syncthreads();

    // ---- X row -> 65 VGPRs (stride-65: bank = lane + m mod 32, 2-way free)
    float X[NF];
    #pragma unroll
    for (int m = 0; m < NF; ++m) X[m] = smem[lane * NF + m];
    __syncthreads();   // all X reads done; Yb overlays this region

    // ---- stage 1: p-range per wave, separate E/O accumulation
    const int pbase = wv * 17;                      // 0 or 17
    const int pcnt  = 17 - wv;                      // 17 or 16
    cfloat* ct = (cfloat*)(unsigned long long)(const float*)d_tab;
    for (int pp = 0; pp < pcnt; ++pp) {
        const int p = pbase + pp;                   // wave-uniform
        cfloat* cf = ct + p * TSTR;
        float e0 = 0.0f, e1 = 0.0f, o0 = 0.0f, o1 = 0.0f;
        #pragma unroll
        for (int m = 0; m < 64; m += 4) {
            e0 += cf[m]     * X[m];
            o0 += cf[m + 1] * X[m + 1];
            e1 += cf[m + 2] * X[m + 2];
            o1 += cf[m + 3] * X[m + 3];
        }
        e0 += cf[64] * X[64];
        const float E = e0 + e1, O = o0 + o1;
        Yb[lane * YSTR + p]      = __float2bfloat16(E + O);
        Yb[lane * YSTR + 64 - p] = __float2bfloat16(E - O);
    }
    __syncthreads();

    // ---- stage 2: 6-tap polyphase, rolling window; frames split 30/29
    const int j = lane;
    float fc[6];
    #pragma unroll
    for (int k = 0; k < 6; ++k) fc[k] = g_filt[k * 64 + j] * (1.0f / 512.0f);
    const int te = j;
    const int to = (j == 0) ? 64 : 64 - j;
    const int qlo = wv * 30;
    const int nq  = 30 - wv;

    float we[6], wo[6];
    #pragma unroll
    for (int r = 0; r < 5; ++r) {
        we[r] = __bfloat162float(Yb[(qlo + r) * YSTR + te]);
        wo[r] = __bfloat162float(Yb[(qlo + r) * YSTR + to]);
    }
    float* dst = g_out + ((size_t)s * TRUE_LEN + fbase + qlo) * 64 + j;

    for (int u = 0; u < nq; ++u) {
        if (fbase + qlo + u >= TRUE_LEN) break;
        we[5] = __bfloat162float(Yb[(qlo + u + 5) * YSTR + te]);
        wo[5] = __bfloat162float(Yb[(qlo + u + 5) * YSTR + to]);
        const float o = fc[0] * we[5] + fc[1] * wo[4] + fc[2] * we[3]
                      + fc[3] * wo[2] + fc[4] * we[1] + fc[5] * wo[0];
        dst[(size_t)u * 64] = o;
        #pragma unroll
        for (int r = 0; r < 5; ++r) { we[r] = we[r + 1]; wo[r] = wo[r + 1]; }
    }
}

extern "C" void kernel_launch(void* const* d_in, const int* in_sizes, int n_in,
                              void* d_out, int out_size, void* d_ws, size_t ws_size,
                              hipStream_t stream) {
    const float* g_in   = (const float*)d_in[0];  // (16,1,8192,65) fp32
    const float* g_filt = (const float*)d_in[1];  // (384,) fp32
    float* g_out = (float*)d_out;                 // (16,1,8187*64) fp32

    build_tab_kernel<<<9, 256, 0, stream>>>();    // 33*68 = 2244 entries
    subband_main_kernel<<<16 * CPB, 128, 0, stream>>>(g_in, g_filt, g_out);
}